// Round 14
// baseline (455.703 us; speedup 1.0000x reference)
//
#include <hip/hip_runtime.h>
#include <cstdint>
#include <cstddef>

#define IN_C  512
#define OUT_C 1024
#define NSAMP 8192
#define KTOT  1536

typedef __bf16 bf16x8 __attribute__((ext_vector_type(8)));
typedef float  f32x4  __attribute__((ext_vector_type(4)));

#define SBAR()   __builtin_amdgcn_s_barrier()
#define SFENCE() __builtin_amdgcn_sched_barrier(0)
#define VM8()    asm volatile("s_waitcnt vmcnt(8)")
#define VM0()    asm volatile("s_waitcnt vmcnt(0)")

__device__ __forceinline__ unsigned short f2bf(float f) {
    unsigned int u = __float_as_uint(f);
    u += 0x7FFFu + ((u >> 16) & 1u);   // round-to-nearest-even
    return (unsigned short)(u >> 16);
}
__device__ __forceinline__ float sigmoid_f(float x) { return 1.0f / (1.0f + __expf(-x)); }
__device__ __forceinline__ float tanh_f(float x) {
    float e = __expf(2.0f * x);
    return 1.0f - 2.0f / (e + 1.0f);
}

// ---- transpose + f32->bf16: in (R x C) row-major -> out (C x R) row-major ----
__global__ void tcvt_kernel(const float* __restrict__ in, unsigned short* __restrict__ out,
                            int R, int C) {
    __shared__ float t[32][33];
    const int tx = threadIdx.x, ty = threadIdx.y;
    const int c0 = blockIdx.x * 32, r0 = blockIdx.y * 32;
#pragma unroll
    for (int i = 0; i < 4; ++i)
        t[ty + i * 8][tx] = in[(size_t)(r0 + ty + i * 8) * C + (c0 + tx)];
    __syncthreads();
#pragma unroll
    for (int i = 0; i < 4; ++i)
        out[(size_t)(c0 + ty + i * 8) * R + (r0 + tx)] = f2bf(t[tx][ty + i * 8]);
}

// ---- pack A'[4096][1536]: row m = out_row*4 + gate; k<512 from wx_g, else wh_g ----
__global__ void packA_kernel(const float* __restrict__ x0, const float* __restrict__ x1,
                             const float* __restrict__ x2, const float* __restrict__ x3,
                             const float* __restrict__ h0, const float* __restrict__ h1,
                             const float* __restrict__ h2, const float* __restrict__ h3,
                             unsigned short* __restrict__ Ap) {
    const int idx = blockIdx.x * 256 + threadIdx.x;   // 4096*192 total (8 k each)
    const int m = idx / 192, k8 = idx % 192;
    const int g = m & 3, r = m >> 2;
    const float* src;
    if (k8 < 64) {
        const float* a = (g & 2) ? ((g & 1) ? x3 : x2) : ((g & 1) ? x1 : x0);
        src = a + (size_t)r * IN_C + k8 * 8;
    } else {
        const float* a = (g & 2) ? ((g & 1) ? h3 : h2) : ((g & 1) ? h1 : h0);
        src = a + (size_t)r * OUT_C + (k8 - 64) * 8;
    }
    float4 v0 = reinterpret_cast<const float4*>(src)[0];
    float4 v1 = reinterpret_cast<const float4*>(src)[1];
    ushort4 o0, o1;
    o0.x = f2bf(v0.x); o0.y = f2bf(v0.y); o0.z = f2bf(v0.z); o0.w = f2bf(v0.w);
    o1.x = f2bf(v1.x); o1.y = f2bf(v1.y); o1.z = f2bf(v1.z); o1.w = f2bf(v1.w);
    ushort4* dst = reinterpret_cast<ushort4*>(Ap + (size_t)m * KTOT + k8 * 8);
    dst[0] = o0; dst[1] = o1;
}

// ---- fused MDLSTM as one 256x256-tile GEMM, 8 waves, 16x16x32 MFMA.
// A-fragments read DIRECTLY from global (L1/L2-resident weight tile) —
// LDS holds only B. A(j+1) prefetched across the barrier (global reads need
// no staging sync). One barrier + one counted vmcnt(8) per K-tile.
__global__ __launch_bounds__(512, 2) void mdlstm_main(
    const unsigned short* __restrict__ Ap,    // [4096][1536] bf16
    const unsigned short* __restrict__ xT,    // [8192][512]  bf16
    const unsigned short* __restrict__ h0T,   // [8192][1024] bf16
    const unsigned short* __restrict__ h1T,   // [8192][1024] bf16
    const float* __restrict__ b_i, const float* __restrict__ b_f,
    const float* __restrict__ b_g, const float* __restrict__ b_o,
    const float* __restrict__ cp0, const float* __restrict__ cp1,
    const float* __restrict__ wsum,
    float* __restrict__ out)
{
    // B-only LDS: 2 bufs x 32KB (dir0 @0, dir1 @16K per buf)
    // each 16KB region = [kk(2)][row(128)][64B], byte-swizzle ((row>>1)&3)<<4
    __shared__ __align__(16) unsigned char smem[65536];

    const int tid  = threadIdx.x;
    const int lane = tid & 63;
    const int wid  = tid >> 6;      // 0..7
    const int wm   = wid >> 2;      // 0..1 : A-half
    const int wn   = wid & 3;       // 0..3 : (dir = wn>>1, sample-half = wn&1)
    const int g4   = lane >> 4;
    const int l16  = lane & 15;

    const int by    = blockIdx.y;         // 0..15
    const int bcol  = blockIdx.x * 128;   // sample base
    const int browM = by * 256;           // A'-row base

    f32x4 acc[8][4];
#pragma unroll
    for (int mf = 0; mf < 8; ++mf)
#pragma unroll
        for (int nf = 0; nf < 4; ++nf)
            acc[mf][nf] = (f32x4){0.f, 0.f, 0.f, 0.f};

    auto stage_B = [&](int P, int d, int j2) {
#pragma unroll
        for (int c = 0; c < 2; ++c) {
            const int u    = c * 8192 + tid * 16;
            const int rloc = (u >> 6) & 127;
            const int kb   = (u & 63) ^ (((u >> 7) & 3) << 4);
            const char* src;
            if (j2 < 8) {   // x-region: both dirs read the same xT tile
                src = (const char*)xT + ((size_t)(bcol + rloc) * IN_C + j2 * 64 + c * 32) * 2 + kb;
            } else {
                const unsigned short* hsrc = d ? h1T : h0T;
                src = (const char*)hsrc + ((size_t)(bcol + rloc) * OUT_C + (j2 - 8) * 64 + c * 32) * 2 + kb;
            }
            __builtin_amdgcn_global_load_lds((const unsigned int*)src,
                (unsigned int*)(smem + P * 32768 + d * 16384 + u), 16, 0, 0);
        }
    };

    auto fragB = [&](int P, int nf, int kk) -> bf16x8 {
        const int row = (wn & 1) * 64 + nf * 16 + l16;
        const int u = kk * 8192 + row * 64 + ((g4 * 16) ^ (((row >> 1) & 3) << 4));
        return *reinterpret_cast<const bf16x8*>(smem + P * 32768 + (wn >> 1) * 16384 + u);
    };

    bf16x8 aA[4][2];   // A frags for 2 clusters (global-sourced), reused mid-tile
    bf16x8 bF[4][2];   // current tile's B frags

    // load A frags mf = mfbase..mfbase+3 of K-tile j into aA (8 global dwordx4)
    auto loadAglobal = [&](int j, int mfbase) {
#pragma unroll
        for (int q = 0; q < 4; ++q)
#pragma unroll
            for (int kk = 0; kk < 2; ++kk) {
                const int row = browM + wm * 128 + (mfbase + q) * 16 + l16;
                aA[q][kk] = *reinterpret_cast<const bf16x8*>(
                    Ap + (size_t)row * KTOT + j * 64 + kk * 32 + g4 * 8);
            }
    };

    auto cluster = [&](int M, int i0) {
        __builtin_amdgcn_s_setprio(1);
#pragma unroll
        for (int kk = 0; kk < 2; ++kk)
#pragma unroll
            for (int mi = 0; mi < 2; ++mi)
#pragma unroll
                for (int nf = 0; nf < 4; ++nf)
                    acc[M + mi][nf] = __builtin_amdgcn_mfma_f32_16x16x32_bf16(
                        aA[i0 + mi][kk], bF[nf][kk], acc[M + mi][nf], 0, 0, 0);
        __builtin_amdgcn_s_setprio(0);
    };
    auto loadB = [&](int P) {
#pragma unroll
        for (int nf = 0; nf < 4; ++nf)
#pragma unroll
            for (int kk = 0; kk < 2; ++kk) bF[nf][kk] = fragB(P, nf, kk);
    };

    // One K-tile, one barrier. aA holds mf0-3 on entry (prefetched last tile).
    auto ktile = [&](int j, int P, int PN, bool last) {
        SFENCE();
        loadB(P);                          // 8 LDS reads (buf P)
        cluster(0, 0);                     // mf0,1
        if (!last) stage_B(PN, 0, j + 1);
        cluster(2, 2);                     // mf2,3
        loadAglobal(j, 4);                 // refill aA with mf4-7 (8 global)
        if (!last) stage_B(PN, 1, j + 1);
        cluster(4, 0);                     // mf4,5
        cluster(6, 2);                     // mf6,7
        if (!last) {
            loadAglobal(j + 1, 0);         // prefetch next tile's mf0-3
            SFENCE(); VM8(); SFENCE();     // 8 youngest = A'; forces B staging done
        } else {
            SFENCE(); VM0(); SFENCE();
        }
        SBAR();
    };

    // ---------------- prologue: stage B(0), prefetch A(0, mf0-3) ----------------
    stage_B(0, 0, 0); stage_B(0, 1, 0);    // 4 loads (oldest)
    loadAglobal(0, 0);                     // 8 loads (youngest)
    SFENCE(); VM8(); SFENCE();             // forces B staging done; A may fly
    SBAR();

    // ---------------- main loop: 24 K-tiles ----------------
#pragma unroll 1
    for (int jj = 0; jj < 12; ++jj) {
        ktile(2 * jj,     0, 1, false);
        ktile(2 * jj + 1, 1, 0, 2 * jj + 1 == 23);
    }

    // ---------------- epilogue: lane-local gates; LDS exchange for dir combine ----
    const float w0 = wsum[0], w1 = wsum[1];
    const int   d  = wn >> 1;
    const float* cp = d ? cp1 : cp0;
    const float wd  = d ? w1 : w0;

    float rc[8][4], rh[8][4];
#pragma unroll
    for (int mf = 0; mf < 8; ++mf) {
        const int orow = by * 64 + wm * 32 + mf * 4 + g4;
        const float bi = b_i[orow], bff = b_f[orow], bg = b_g[orow], bo = b_o[orow];
#pragma unroll
        for (int nf = 0; nf < 4; ++nf) {
            const int scol = bcol + (wn & 1) * 64 + nf * 16 + l16;
            float i_ = sigmoid_f(acc[mf][nf][0] + bi);
            float f_ = sigmoid_f(acc[mf][nf][1] + bff);
            float g_ = tanh_f  (acc[mf][nf][2] + bg);
            float o_ = sigmoid_f(acc[mf][nf][3] + bo);
            float cc = f_ * cp[(size_t)orow * NSAMP + scol] + i_ * g_;
            float hh = o_ * tanh_f(cc);
            rc[mf][nf] = wd * cc;
            rh[mf][nf] = wd * hh;
        }
    }

    float* ex = (float*)smem;
    const int rbase = (wm * 2 + (wn & 1)) * 4096;   // 16KB float region per (wm, sample-half)
    if (d == 1) {
#pragma unroll
        for (int mf = 0; mf < 8; ++mf)
#pragma unroll
            for (int nf = 0; nf < 4; ++nf) {
                const int slot = rbase + (mf * 4 + nf) * 64 + lane;
                ex[slot]        = rc[mf][nf];
                ex[slot + 2048] = rh[mf][nf];
            }
    }
    SBAR();
    if (d == 0) {
#pragma unroll
        for (int mf = 0; mf < 8; ++mf) {
            const int orow = by * 64 + wm * 32 + mf * 4 + g4;
#pragma unroll
            for (int nf = 0; nf < 4; ++nf) {
                const int scol = bcol + (wn & 1) * 64 + nf * 16 + l16;
                const int slot = rbase + (mf * 4 + nf) * 64 + lane;
                out[(size_t)orow * NSAMP + scol] = rc[mf][nf] + ex[slot];
                out[(size_t)OUT_C * NSAMP + (size_t)orow * NSAMP + scol] = rh[mf][nf] + ex[slot + 2048];
            }
        }
    }
}

extern "C" void kernel_launch(void* const* d_in, const int* in_sizes, int n_in,
                              void* d_out, int out_size, void* d_ws, size_t ws_size,
                              hipStream_t stream) {
    (void)in_sizes; (void)n_in; (void)out_size; (void)ws_size;

    const float* x    = (const float*)d_in[0];
    const float* cp0  = (const float*)d_in[1];
    const float* hp0  = (const float*)d_in[2];
    const float* cp1  = (const float*)d_in[3];
    const float* hp1  = (const float*)d_in[4];
    const float* b_i  = (const float*)d_in[13];
    const float* b_f  = (const float*)d_in[14];
    const float* b_g  = (const float*)d_in[15];
    const float* b_o  = (const float*)d_in[16];
    const float* wsum = (const float*)d_in[17];
    float* out = (float*)d_out;

    // workspace: xT 8MB @0, h0T 16MB @8M, h1T 16MB @24M, Ap 12MB @40M
    char* ws = (char*)d_ws;
    unsigned short* xT  = (unsigned short*)(ws);
    unsigned short* h0T = (unsigned short*)(ws + (size_t)8  * 1024 * 1024);
    unsigned short* h1T = (unsigned short*)(ws + (size_t)24 * 1024 * 1024);
    unsigned short* Ap  = (unsigned short*)(ws + (size_t)40 * 1024 * 1024);

    dim3 tb(32, 8);
    tcvt_kernel<<<dim3(NSAMP / 32, IN_C  / 32), tb, 0, stream>>>(x,   xT,  IN_C,  NSAMP);
    tcvt_kernel<<<dim3(NSAMP / 32, OUT_C / 32), tb, 0, stream>>>(hp0, h0T, OUT_C, NSAMP);
    tcvt_kernel<<<dim3(NSAMP / 32, OUT_C / 32), tb, 0, stream>>>(hp1, h1T, OUT_C, NSAMP);

    packA_kernel<<<(4096 * 192) / 256, 256, 0, stream>>>(
        (const float*)d_in[5], (const float*)d_in[6], (const float*)d_in[7], (const float*)d_in[8],
        (const float*)d_in[9], (const float*)d_in[10], (const float*)d_in[11], (const float*)d_in[12],
        Ap);

    mdlstm_main<<<dim3(NSAMP / 128, OUT_C / 64), 512, 0, stream>>>(
        Ap, xT, h0T, h1T, b_i, b_f, b_g, b_o, cp0, cp1, wsum, out);
}

// Round 15
// 395.547 us; speedup vs baseline: 1.1521x; 1.1521x over previous
//
#include <hip/hip_runtime.h>
#include <cstdint>
#include <cstddef>

#define IN_C  512
#define OUT_C 1024
#define NSAMP 8192
#define KTOT  1536

typedef __bf16 bf16x8 __attribute__((ext_vector_type(8)));
typedef float  f32x4  __attribute__((ext_vector_type(4)));

#define SBAR()   __builtin_amdgcn_s_barrier()
#define SFENCE() __builtin_amdgcn_sched_barrier(0)
#define VM0()    asm volatile("s_waitcnt vmcnt(0)")

__device__ __forceinline__ unsigned short f2bf(float f) {
    unsigned int u = __float_as_uint(f);
    u += 0x7FFFu + ((u >> 16) & 1u);   // round-to-nearest-even
    return (unsigned short)(u >> 16);
}
__device__ __forceinline__ float sigmoid_f(float x) { return 1.0f / (1.0f + __expf(-x)); }
__device__ __forceinline__ float tanh_f(float x) {
    float e = __expf(2.0f * x);
    return 1.0f - 2.0f / (e + 1.0f);
}

// ---- transpose + f32->bf16: in (R x C) row-major -> out (C x R) row-major ----
__global__ void tcvt_kernel(const float* __restrict__ in, unsigned short* __restrict__ out,
                            int R, int C) {
    __shared__ float t[32][33];
    const int tx = threadIdx.x, ty = threadIdx.y;
    const int c0 = blockIdx.x * 32, r0 = blockIdx.y * 32;
#pragma unroll
    for (int i = 0; i < 4; ++i)
        t[ty + i * 8][tx] = in[(size_t)(r0 + ty + i * 8) * C + (c0 + tx)];
    __syncthreads();
#pragma unroll
    for (int i = 0; i < 4; ++i)
        out[(size_t)(c0 + ty + i * 8) * R + (r0 + tx)] = f2bf(t[tx][ty + i * 8]);
}

// ---- pack A'[4096][1536]: row m = out_row*4 + gate; k<512 from wx_g, else wh_g ----
__global__ void packA_kernel(const float* __restrict__ x0, const float* __restrict__ x1,
                             const float* __restrict__ x2, const float* __restrict__ x3,
                             const float* __restrict__ h0, const float* __restrict__ h1,
                             const float* __restrict__ h2, const float* __restrict__ h3,
                             unsigned short* __restrict__ Ap) {
    const int idx = blockIdx.x * 256 + threadIdx.x;   // 4096*192 total (8 k each)
    const int m = idx / 192, k8 = idx % 192;
    const int g = m & 3, r = m >> 2;
    const float* src;
    if (k8 < 64) {
        const float* a = (g & 2) ? ((g & 1) ? x3 : x2) : ((g & 1) ? x1 : x0);
        src = a + (size_t)r * IN_C + k8 * 8;
    } else {
        const float* a = (g & 2) ? ((g & 1) ? h3 : h2) : ((g & 1) ? h1 : h0);
        src = a + (size_t)r * OUT_C + (k8 - 64) * 8;
    }
    float4 v0 = reinterpret_cast<const float4*>(src)[0];
    float4 v1 = reinterpret_cast<const float4*>(src)[1];
    ushort4 o0, o1;
    o0.x = f2bf(v0.x); o0.y = f2bf(v0.y); o0.z = f2bf(v0.z); o0.w = f2bf(v0.w);
    o1.x = f2bf(v1.x); o1.y = f2bf(v1.y); o1.z = f2bf(v1.z); o1.w = f2bf(v1.w);
    ushort4* dst = reinterpret_cast<ushort4*>(Ap + (size_t)m * KTOT + k8 * 8);
    dst[0] = o0; dst[1] = o1;
}

// ---- fused MDLSTM as one 256x256-tile GEMM, 8 waves, 16x16x32 MFMA.
// One barrier per K-tile + sched_barrier(0)-pinned alternation of
// {LDS-read regions} and {MFMA-burst regions}: reads for cluster c+2 are
// issued in their own region BEFORE the burst of cluster c, so the LDS pipe
// services them while the matrix pipe drains the burst.
__global__ __launch_bounds__(512, 2) void mdlstm_main(
    const unsigned short* __restrict__ Ap,    // [4096][1536] bf16
    const unsigned short* __restrict__ xT,    // [8192][512]  bf16
    const unsigned short* __restrict__ h0T,   // [8192][1024] bf16
    const unsigned short* __restrict__ h1T,   // [8192][1024] bf16
    const float* __restrict__ b_i, const float* __restrict__ b_f,
    const float* __restrict__ b_g, const float* __restrict__ b_o,
    const float* __restrict__ cp0, const float* __restrict__ cp1,
    const float* __restrict__ wsum,
    float* __restrict__ out)
{
    // 2 bufs x 64KB: A(half0)@0, A(half1)@16K, B(dir0)@32K, B(dir1)@48K
    // each 16KB region = [kk(2)][row(128)][64B], byte-swizzle ((row>>1)&3)<<4
    __shared__ __align__(16) unsigned char smem[131072];

    const int tid  = threadIdx.x;
    const int lane = tid & 63;
    const int wid  = tid >> 6;      // 0..7
    const int wm   = wid >> 2;      // 0..1 : A-half
    const int wn   = wid & 3;       // 0..3 : (dir = wn>>1, sample-half = wn&1)
    const int g4   = lane >> 4;
    const int l16  = lane & 15;

    const int by    = blockIdx.y;         // 0..15
    const int bcol  = blockIdx.x * 128;   // sample base
    const int browM = by * 256;           // A'-row base

    f32x4 acc[8][4];
#pragma unroll
    for (int mf = 0; mf < 8; ++mf)
#pragma unroll
        for (int nf = 0; nf < 4; ++nf)
            acc[mf][nf] = (f32x4){0.f, 0.f, 0.f, 0.f};

    auto stage_A = [&](int P, int hA, int j1) {
#pragma unroll
        for (int c = 0; c < 2; ++c) {
            const int u    = c * 8192 + tid * 16;
            const int rloc = (u >> 6) & 127;
            const int kb   = (u & 63) ^ (((u >> 7) & 3) << 4);
            const char* src = (const char*)Ap
                + ((size_t)(browM + hA * 128 + rloc) * KTOT + j1 * 64 + c * 32) * 2 + kb;
            __builtin_amdgcn_global_load_lds((const unsigned int*)src,
                (unsigned int*)(smem + P * 65536 + hA * 16384 + u), 16, 0, 0);
        }
    };
    auto stage_B = [&](int P, int d, int j2) {
#pragma unroll
        for (int c = 0; c < 2; ++c) {
            const int u    = c * 8192 + tid * 16;
            const int rloc = (u >> 6) & 127;
            const int kb   = (u & 63) ^ (((u >> 7) & 3) << 4);
            const char* src;
            if (j2 < 8) {   // x-region: both dirs read the same xT tile
                src = (const char*)xT + ((size_t)(bcol + rloc) * IN_C + j2 * 64 + c * 32) * 2 + kb;
            } else {
                const unsigned short* hsrc = d ? h1T : h0T;
                src = (const char*)hsrc + ((size_t)(bcol + rloc) * OUT_C + (j2 - 8) * 64 + c * 32) * 2 + kb;
            }
            __builtin_amdgcn_global_load_lds((const unsigned int*)src,
                (unsigned int*)(smem + P * 65536 + 32768 + d * 16384 + u), 16, 0, 0);
        }
    };

    auto swzb = [](int u) { return u ^ (((u >> 7) & 3) << 4); };
    auto fragA = [&](int P, int mf, int kk) -> bf16x8 {
        const int u = kk * 8192 + (mf * 16 + l16) * 64 + g4 * 16;
        return *reinterpret_cast<const bf16x8*>(smem + P * 65536 + wm * 16384 + swzb(u));
    };
    auto fragB = [&](int P, int nf, int kk) -> bf16x8 {
        const int u = kk * 8192 + ((wn & 1) * 64 + nf * 16 + l16) * 64 + g4 * 16;
        return *reinterpret_cast<const bf16x8*>(smem + P * 65536 + 32768 + (wn >> 1) * 16384 + swzb(u));
    };

    bf16x8 Ra[2][2], Rb[2][2], Rc[2][2];   // 3 static A-frag sets (read-ahead)
    bf16x8 bF[4][2];                       // current tile's B frags

    auto cluster = [&](bf16x8 (&aF)[2][2], int M) {
        __builtin_amdgcn_s_setprio(1);
#pragma unroll
        for (int kk = 0; kk < 2; ++kk)
#pragma unroll
            for (int mi = 0; mi < 2; ++mi)
#pragma unroll
                for (int nf = 0; nf < 4; ++nf)
                    acc[M + mi][nf] = __builtin_amdgcn_mfma_f32_16x16x32_bf16(
                        aF[mi][kk], bF[nf][kk], acc[M + mi][nf], 0, 0, 0);
        __builtin_amdgcn_s_setprio(0);
    };
    auto loadA = [&](bf16x8 (&aF)[2][2], int P, int mf) {
#pragma unroll
        for (int kk = 0; kk < 2; ++kk) { aF[0][kk] = fragA(P, mf, kk); aF[1][kk] = fragA(P, mf + 1, kk); }
    };
    auto loadB = [&](int P) {
#pragma unroll
        for (int nf = 0; nf < 4; ++nf)
#pragma unroll
            for (int kk = 0; kk < 2; ++kk) bF[nf][kk] = fragB(P, nf, kk);
    };

    // One K-tile, one barrier, 7 fence-pinned regions alternating reads/MFMA.
    auto ktile = [&](int j, int P, int PN) {
        const bool st = (j < 23);
        // R0: B frags + A(c0)->Ra + A(c1)->Rb   (16 ds_reads)
        loadB(P);
        loadA(Ra, P, 0);
        loadA(Rb, P, 2);
        SFENCE();
        // R1: A(c2)->Rc ; stage A(j+1)
        loadA(Rc, P, 4);
        if (st) { stage_A(PN, 0, j + 1); stage_A(PN, 1, j + 1); }
        SFENCE();
        // R2: burst c0 (Ra)  — LDS services R1's reads during this drain
        cluster(Ra, 0);
        SFENCE();
        // R3: A(c3)->Ra ; stage B(j+1)   (Ra free: c0 fully issued)
        loadA(Ra, P, 6);
        if (st) { stage_B(PN, 0, j + 1); stage_B(PN, 1, j + 1); }
        SFENCE();
        // R4: burst c1 (Rb) — covers R3's reads
        cluster(Rb, 2);
        SFENCE();
        // R5: burst c2 (Rc)
        cluster(Rc, 4);
        SFENCE();
        // R6: burst c3 (Ra) ; drain staging ; barrier
        cluster(Ra, 6);
        SFENCE(); VM0(); SFENCE();
        SBAR();
    };

    // ---------------- prologue: stage tile 0 ----------------
    stage_A(0, 0, 0); stage_A(0, 1, 0);
    stage_B(0, 0, 0); stage_B(0, 1, 0);
    SFENCE(); VM0(); SFENCE();
    SBAR();

    // ---------------- main loop: 24 K-tiles ----------------
#pragma unroll 1
    for (int jj = 0; jj < 12; ++jj) {
        ktile(2 * jj,     0, 1);
        ktile(2 * jj + 1, 1, 0);
    }

    // ---------------- epilogue: lane-local gates; LDS exchange for dir combine ----
    const float w0 = wsum[0], w1 = wsum[1];
    const int   d  = wn >> 1;
    const float* cp = d ? cp1 : cp0;
    const float wd  = d ? w1 : w0;

    float rc[8][4], rh[8][4];
#pragma unroll
    for (int mf = 0; mf < 8; ++mf) {
        const int orow = by * 64 + wm * 32 + mf * 4 + g4;
        const float bi = b_i[orow], bff = b_f[orow], bg = b_g[orow], bo = b_o[orow];
#pragma unroll
        for (int nf = 0; nf < 4; ++nf) {
            const int scol = bcol + (wn & 1) * 64 + nf * 16 + l16;
            float i_ = sigmoid_f(acc[mf][nf][0] + bi);
            float f_ = sigmoid_f(acc[mf][nf][1] + bff);
            float g_ = tanh_f  (acc[mf][nf][2] + bg);
            float o_ = sigmoid_f(acc[mf][nf][3] + bo);
            float cc = f_ * cp[(size_t)orow * NSAMP + scol] + i_ * g_;
            float hh = o_ * tanh_f(cc);
            rc[mf][nf] = wd * cc;
            rh[mf][nf] = wd * hh;
        }
    }

    float* ex = (float*)smem;
    const int rbase = (wm * 2 + (wn & 1)) * 4096;   // 16KB region per (wm, sample-half)
    if (d == 1) {
#pragma unroll
        for (int mf = 0; mf < 8; ++mf)
#pragma unroll
            for (int nf = 0; nf < 4; ++nf) {
                const int slot = rbase + (mf * 4 + nf) * 64 + lane;
                ex[slot]        = rc[mf][nf];
                ex[slot + 2048] = rh[mf][nf];
            }
    }
    SBAR();
    if (d == 0) {
#pragma unroll
        for (int mf = 0; mf < 8; ++mf) {
            const int orow = by * 64 + wm * 32 + mf * 4 + g4;
#pragma unroll
            for (int nf = 0; nf < 4; ++nf) {
                const int scol = bcol + (wn & 1) * 64 + nf * 16 + l16;
                const int slot = rbase + (mf * 4 + nf) * 64 + lane;
                out[(size_t)orow * NSAMP + scol] = rc[mf][nf] + ex[slot];
                out[(size_t)OUT_C * NSAMP + (size_t)orow * NSAMP + scol] = rh[mf][nf] + ex[slot + 2048];
            }
        }
    }
}

extern "C" void kernel_launch(void* const* d_in, const int* in_sizes, int n_in,
                              void* d_out, int out_size, void* d_ws, size_t ws_size,
                              hipStream_t stream) {
    (void)in_sizes; (void)n_in; (void)out_size; (void)ws_size;

    const float* x    = (const float*)d_in[0];
    const float* cp0  = (const float*)d_in[1];
    const float* hp0  = (const float*)d_in[2];
    const float* cp1  = (const float*)d_in[3];
    const float* hp1  = (const float*)d_in[4];
    const float* b_i  = (const float*)d_in[13];
    const float* b_f  = (const float*)d_in[14];
    const float* b_g  = (const float*)d_in[15];
    const float* b_o  = (const float*)d_in[16];
    const float* wsum = (const float*)d_in[17];
    float* out = (float*)d_out;

    // workspace: xT 8MB @0, h0T 16MB @8M, h1T 16MB @24M, Ap 12MB @40M
    char* ws = (char*)d_ws;
    unsigned short* xT  = (unsigned short*)(ws);
    unsigned short* h0T = (unsigned short*)(ws + (size_t)8  * 1024 * 1024);
    unsigned short* h1T = (unsigned short*)(ws + (size_t)24 * 1024 * 1024);
    unsigned short* Ap  = (unsigned short*)(ws + (size_t)40 * 1024 * 1024);

    dim3 tb(32, 8);
    tcvt_kernel<<<dim3(NSAMP / 32, IN_C  / 32), tb, 0, stream>>>(x,   xT,  IN_C,  NSAMP);
    tcvt_kernel<<<dim3(NSAMP / 32, OUT_C / 32), tb, 0, stream>>>(hp0, h0T, OUT_C, NSAMP);
    tcvt_kernel<<<dim3(NSAMP / 32, OUT_C / 32), tb, 0, stream>>>(hp1, h1T, OUT_C, NSAMP);

    packA_kernel<<<(4096 * 192) / 256, 256, 0, stream>>>(
        (const float*)d_in[5], (const float*)d_in[6], (const float*)d_in[7], (const float*)d_in[8],
        (const float*)d_in[9], (const float*)d_in[10], (const float*)d_in[11], (const float*)d_in[12],
        Ap);

    mdlstm_main<<<dim3(NSAMP / 128, OUT_C / 64), 512, 0, stream>>>(
        Ap, xT, h0T, h1T, b_i, b_f, b_g, b_o, cp0, cp1, wsum, out);
}

// Round 16
// 278.765 us; speedup vs baseline: 1.6347x; 1.4189x over previous
//
#include <hip/hip_runtime.h>
#include <cstdint>
#include <cstddef>

#define IN_C  512
#define OUT_C 1024
#define NSAMP 8192
#define KTOT  1536

typedef __bf16 bf16x8 __attribute__((ext_vector_type(8)));
typedef float  f32x4  __attribute__((ext_vector_type(4)));

#define SBAR()   __builtin_amdgcn_s_barrier()
#define SFENCE() __builtin_amdgcn_sched_barrier(0)
#define VM0()    asm volatile("s_waitcnt vmcnt(0)")

__device__ __forceinline__ unsigned short f2bf(float f) {
    unsigned int u = __float_as_uint(f);
    u += 0x7FFFu + ((u >> 16) & 1u);   // round-to-nearest-even
    return (unsigned short)(u >> 16);
}
__device__ __forceinline__ float sigmoid_f(float x) { return 1.0f / (1.0f + __expf(-x)); }
__device__ __forceinline__ float tanh_f(float x) {
    float e = __expf(2.0f * x);
    return 1.0f - 2.0f / (e + 1.0f);
}

// ---- transpose + f32->bf16: in (R x C) row-major -> out (C x R) row-major ----
__global__ void tcvt_kernel(const float* __restrict__ in, unsigned short* __restrict__ out,
                            int R, int C) {
    __shared__ float t[32][33];
    const int tx = threadIdx.x, ty = threadIdx.y;
    const int c0 = blockIdx.x * 32, r0 = blockIdx.y * 32;
#pragma unroll
    for (int i = 0; i < 4; ++i)
        t[ty + i * 8][tx] = in[(size_t)(r0 + ty + i * 8) * C + (c0 + tx)];
    __syncthreads();
#pragma unroll
    for (int i = 0; i < 4; ++i)
        out[(size_t)(c0 + ty + i * 8) * R + (r0 + tx)] = f2bf(t[tx][ty + i * 8]);
}

// ---- pack A'[4096][1536]: row m = out_row*4 + gate; k<512 from wx_g, else wh_g ----
__global__ void packA_kernel(const float* __restrict__ x0, const float* __restrict__ x1,
                             const float* __restrict__ x2, const float* __restrict__ x3,
                             const float* __restrict__ h0, const float* __restrict__ h1,
                             const float* __restrict__ h2, const float* __restrict__ h3,
                             unsigned short* __restrict__ Ap) {
    const int idx = blockIdx.x * 256 + threadIdx.x;   // 4096*192 total (8 k each)
    const int m = idx / 192, k8 = idx % 192;
    const int g = m & 3, r = m >> 2;
    const float* src;
    if (k8 < 64) {
        const float* a = (g & 2) ? ((g & 1) ? x3 : x2) : ((g & 1) ? x1 : x0);
        src = a + (size_t)r * IN_C + k8 * 8;
    } else {
        const float* a = (g & 2) ? ((g & 1) ? h3 : h2) : ((g & 1) ? h1 : h0);
        src = a + (size_t)r * OUT_C + (k8 - 64) * 8;
    }
    float4 v0 = reinterpret_cast<const float4*>(src)[0];
    float4 v1 = reinterpret_cast<const float4*>(src)[1];
    ushort4 o0, o1;
    o0.x = f2bf(v0.x); o0.y = f2bf(v0.y); o0.z = f2bf(v0.z); o0.w = f2bf(v0.w);
    o1.x = f2bf(v1.x); o1.y = f2bf(v1.y); o1.z = f2bf(v1.z); o1.w = f2bf(v1.w);
    ushort4* dst = reinterpret_cast<ushort4*>(Ap + (size_t)m * KTOT + k8 * 8);
    dst[0] = o0; dst[1] = o1;
}

// ---- fused MDLSTM GEMM: SMALL blocks (4 waves, 64KB LDS) so 2 independent
// blocks co-reside per CU — their unsynchronized barrier domains let one
// block's MFMA bursts overlap the other's LDS/barrier windows (m114 mechanism).
// Block tile: 128 gate-rows x (64 samples x 2 dirs); per-wave 64x64 (acc 64).
__global__ __launch_bounds__(256, 2) void mdlstm_main(
    const unsigned short* __restrict__ Ap,    // [4096][1536] bf16
    const unsigned short* __restrict__ xT,    // [8192][512]  bf16
    const unsigned short* __restrict__ h0T,   // [8192][1024] bf16
    const unsigned short* __restrict__ h1T,   // [8192][1024] bf16
    const float* __restrict__ b_i, const float* __restrict__ b_f,
    const float* __restrict__ b_g, const float* __restrict__ b_o,
    const float* __restrict__ cp0, const float* __restrict__ cp1,
    const float* __restrict__ wsum,
    float* __restrict__ out)
{
    // 2 bufs x 32KB: A[kk2][128][64B] @0 (16KB), B dir0 [kk2][64][64B] @16K, dir1 @24K
    // byte-swizzle ((row>>1)&3)<<4 on the 16B slot within each 64B row
    __shared__ __align__(16) unsigned char smem[65536];

    const int tid  = threadIdx.x;
    const int lane = tid & 63;
    const int wid  = tid >> 6;      // 0..3
    const int dir  = wid & 1;       // dir handled by this wave
    const int wm   = wid >> 1;      // 0..1 : A-half (64 gate-rows)
    const int g4   = lane >> 4;
    const int l16  = lane & 15;

    const int by    = blockIdx.y;         // 0..31
    const int bcol  = blockIdx.x * 64;    // sample base
    const int browM = by * 128;           // A'-row base

    f32x4 acc[4][4];
#pragma unroll
    for (int mf = 0; mf < 4; ++mf)
#pragma unroll
        for (int nf = 0; nf < 4; ++nf)
            acc[mf][nf] = (f32x4){0.f, 0.f, 0.f, 0.f};

    auto stage_A = [&](int P, int j1) {
#pragma unroll
        for (int c = 0; c < 4; ++c) {
            const int u    = c * 4096 + tid * 16;
            const int kk   = u >> 13;
            const int rloc = (u >> 6) & 127;
            const int kb   = u & 63;
            const char* src = (const char*)Ap
                + ((size_t)(browM + rloc) * KTOT + j1 * 64 + kk * 32) * 2
                + (kb ^ (((rloc >> 1) & 3) << 4));
            __builtin_amdgcn_global_load_lds((const unsigned int*)src,
                (unsigned int*)(smem + P * 32768 + u), 16, 0, 0);
        }
    };
    auto stage_B = [&](int P, int d, int j2) {
#pragma unroll
        for (int c = 0; c < 2; ++c) {
            const int u    = c * 4096 + tid * 16;
            const int rloc = (u >> 6) & 63;
            const int kb   = u & 63;
            const char* src;
            if (j2 < 8) {   // x-region: both dirs read the same xT tile
                src = (const char*)xT + ((size_t)(bcol + rloc) * IN_C + j2 * 64 + c * 32) * 2
                      + (kb ^ (((rloc >> 1) & 3) << 4));
            } else {
                const unsigned short* hsrc = d ? h1T : h0T;
                src = (const char*)hsrc + ((size_t)(bcol + rloc) * OUT_C + (j2 - 8) * 64 + c * 32) * 2
                      + (kb ^ (((rloc >> 1) & 3) << 4));
            }
            __builtin_amdgcn_global_load_lds((const unsigned int*)src,
                (unsigned int*)(smem + P * 32768 + 16384 + d * 8192 + u), 16, 0, 0);
        }
    };

    auto fragA = [&](int P, int mf, int kk) -> bf16x8 {
        const int row = wm * 64 + mf * 16 + l16;
        const int u = kk * 8192 + row * 64 + ((g4 * 16) ^ (((row >> 1) & 3) << 4));
        return *reinterpret_cast<const bf16x8*>(smem + P * 32768 + u);
    };
    auto fragB = [&](int P, int nf, int kk) -> bf16x8 {
        const int row = nf * 16 + l16;
        const int u = kk * 4096 + row * 64 + ((g4 * 16) ^ (((row >> 1) & 3) << 4));
        return *reinterpret_cast<const bf16x8*>(smem + P * 32768 + 16384 + dir * 8192 + u);
    };

    bf16x8 aFa[2][2], aFb[2][2];   // two A-frag pairs (mf pairs)
    bf16x8 bF[4][2];               // this dir's B frags for the tile

    auto cluster = [&](bf16x8 (&aF)[2][2], int M) {
        __builtin_amdgcn_s_setprio(1);
#pragma unroll
        for (int kk = 0; kk < 2; ++kk)
#pragma unroll
            for (int mi = 0; mi < 2; ++mi)
#pragma unroll
                for (int nf = 0; nf < 4; ++nf)
                    acc[M + mi][nf] = __builtin_amdgcn_mfma_f32_16x16x32_bf16(
                        aF[mi][kk], bF[nf][kk], acc[M + mi][nf], 0, 0, 0);
        __builtin_amdgcn_s_setprio(0);
    };
    auto loadA = [&](bf16x8 (&aF)[2][2], int P, int mf) {
#pragma unroll
        for (int kk = 0; kk < 2; ++kk) { aF[0][kk] = fragA(P, mf, kk); aF[1][kk] = fragA(P, mf + 1, kk); }
    };
    auto loadB = [&](int P) {
#pragma unroll
        for (int nf = 0; nf < 4; ++nf)
#pragma unroll
            for (int kk = 0; kk < 2; ++kk) bF[nf][kk] = fragB(P, nf, kk);
    };

    // One K-tile, one barrier (r12 chunk structure).
    auto ktile = [&](int j, int P, int PN) {
        const bool st = (j < 23);
        loadB(P);
        loadA(aFa, P, 0);
        cluster(aFa, 0);
        loadA(aFb, P, 2);
        if (st) { stage_A(PN, j + 1); stage_B(PN, 0, j + 1); stage_B(PN, 1, j + 1); }
        cluster(aFb, 2);
        SFENCE(); VM0(); SFENCE();
        SBAR();
    };

    // ---------------- prologue: stage tile 0 ----------------
    stage_A(0, 0);
    stage_B(0, 0, 0); stage_B(0, 1, 0);
    SFENCE(); VM0(); SFENCE();
    SBAR();

    // ---------------- main loop: 24 K-tiles ----------------
#pragma unroll 1
    for (int jj = 0; jj < 12; ++jj) {
        ktile(2 * jj,     0, 1);
        ktile(2 * jj + 1, 1, 0);
    }

    // ---------------- epilogue: lane-local gates; LDS exchange for dir combine ----
    const float wd  = wsum[dir];
    const float* cp = dir ? cp1 : cp0;

    float rc[4][4], rh[4][4];
#pragma unroll
    for (int mf = 0; mf < 4; ++mf) {
        const int orow = by * 32 + wm * 16 + mf * 4 + g4;
        const float bi = b_i[orow], bff = b_f[orow], bg = b_g[orow], bo = b_o[orow];
#pragma unroll
        for (int nf = 0; nf < 4; ++nf) {
            const int scol = bcol + nf * 16 + l16;
            float i_ = sigmoid_f(acc[mf][nf][0] + bi);
            float f_ = sigmoid_f(acc[mf][nf][1] + bff);
            float g_ = tanh_f  (acc[mf][nf][2] + bg);
            float o_ = sigmoid_f(acc[mf][nf][3] + bo);
            float cc = f_ * cp[(size_t)orow * NSAMP + scol] + i_ * g_;
            float hh = o_ * tanh_f(cc);
            rc[mf][nf] = wd * cc;
            rh[mf][nf] = wd * hh;
        }
    }

    float* ex = (float*)smem;
    if (dir == 1) {
#pragma unroll
        for (int mf = 0; mf < 4; ++mf)
#pragma unroll
            for (int nf = 0; nf < 4; ++nf) {
                const int slot = wm * 1024 + (mf * 4 + nf) * 64 + lane;
                ex[slot]        = rc[mf][nf];
                ex[slot + 2048] = rh[mf][nf];
            }
    }
    SBAR();
    if (dir == 0) {
#pragma unroll
        for (int mf = 0; mf < 4; ++mf) {
            const int orow = by * 32 + wm * 16 + mf * 4 + g4;
#pragma unroll
            for (int nf = 0; nf < 4; ++nf) {
                const int scol = bcol + nf * 16 + l16;
                const int slot = wm * 1024 + (mf * 4 + nf) * 64 + lane;
                out[(size_t)orow * NSAMP + scol] = rc[mf][nf] + ex[slot];
                out[(size_t)OUT_C * NSAMP + (size_t)orow * NSAMP + scol] = rh[mf][nf] + ex[slot + 2048];
            }
        }
    }
}

extern "C" void kernel_launch(void* const* d_in, const int* in_sizes, int n_in,
                              void* d_out, int out_size, void* d_ws, size_t ws_size,
                              hipStream_t stream) {
    (void)in_sizes; (void)n_in; (void)out_size; (void)ws_size;

    const float* x    = (const float*)d_in[0];
    const float* cp0  = (const float*)d_in[1];
    const float* hp0  = (const float*)d_in[2];
    const float* cp1  = (const float*)d_in[3];
    const float* hp1  = (const float*)d_in[4];
    const float* b_i  = (const float*)d_in[13];
    const float* b_f  = (const float*)d_in[14];
    const float* b_g  = (const float*)d_in[15];
    const float* b_o  = (const float*)d_in[16];
    const float* wsum = (const float*)d_in[17];
    float* out = (float*)d_out;

    // workspace: xT 8MB @0, h0T 16MB @8M, h1T 16MB @24M, Ap 12MB @40M
    char* ws = (char*)d_ws;
    unsigned short* xT  = (unsigned short*)(ws);
    unsigned short* h0T = (unsigned short*)(ws + (size_t)8  * 1024 * 1024);
    unsigned short* h1T = (unsigned short*)(ws + (size_t)24 * 1024 * 1024);
    unsigned short* Ap  = (unsigned short*)(ws + (size_t)40 * 1024 * 1024);

    dim3 tb(32, 8);
    tcvt_kernel<<<dim3(NSAMP / 32, IN_C  / 32), tb, 0, stream>>>(x,   xT,  IN_C,  NSAMP);
    tcvt_kernel<<<dim3(NSAMP / 32, OUT_C / 32), tb, 0, stream>>>(hp0, h0T, OUT_C, NSAMP);
    tcvt_kernel<<<dim3(NSAMP / 32, OUT_C / 32), tb, 0, stream>>>(hp1, h1T, OUT_C, NSAMP);

    packA_kernel<<<(4096 * 192) / 256, 256, 0, stream>>>(
        (const float*)d_in[5], (const float*)d_in[6], (const float*)d_in[7], (const float*)d_in[8],
        (const float*)d_in[9], (const float*)d_in[10], (const float*)d_in[11], (const float*)d_in[12],
        Ap);

    mdlstm_main<<<dim3(NSAMP / 64, OUT_C / 32), 256, 0, stream>>>(
        Ap, xT, h0T, h1T, b_i, b_f, b_g, b_o, cp0, cp1, wsum, out);
}

// Round 17
// 236.507 us; speedup vs baseline: 1.9268x; 1.1787x over previous
//
#include <hip/hip_runtime.h>
#include <cstdint>
#include <cstddef>

#define IN_C  512
#define OUT_C 1024
#define NSAMP 8192
#define KTOT  1536

typedef __bf16 bf16x8 __attribute__((ext_vector_type(8)));
typedef float  f32x4  __attribute__((ext_vector_type(4)));

#define SBAR()   __builtin_amdgcn_s_barrier()
#define SFENCE() __builtin_amdgcn_sched_barrier(0)
#define VM0()    asm volatile("s_waitcnt vmcnt(0)")

__device__ __forceinline__ unsigned short f2bf(float f) {
    unsigned int u = __float_as_uint(f);
    u += 0x7FFFu + ((u >> 16) & 1u);   // round-to-nearest-even
    return (unsigned short)(u >> 16);
}
__device__ __forceinline__ float sigmoid_f(float x) { return 1.0f / (1.0f + __expf(-x)); }
__device__ __forceinline__ float tanh_f(float x) {
    float e = __expf(2.0f * x);
    return 1.0f - 2.0f / (e + 1.0f);
}

// ---- transpose + f32->bf16: in (R x C) row-major -> out (C x R) row-major ----
__global__ void tcvt_kernel(const float* __restrict__ in, unsigned short* __restrict__ out,
                            int R, int C) {
    __shared__ float t[32][33];
    const int tx = threadIdx.x, ty = threadIdx.y;
    const int c0 = blockIdx.x * 32, r0 = blockIdx.y * 32;
#pragma unroll
    for (int i = 0; i < 4; ++i)
        t[ty + i * 8][tx] = in[(size_t)(r0 + ty + i * 8) * C + (c0 + tx)];
    __syncthreads();
#pragma unroll
    for (int i = 0; i < 4; ++i)
        out[(size_t)(c0 + ty + i * 8) * R + (r0 + tx)] = f2bf(t[tx][ty + i * 8]);
}

// ---- pack A'[4096][1536]: row m = out_row*4 + gate; k<512 from wx_g, else wh_g ----
__global__ void packA_kernel(const float* __restrict__ x0, const float* __restrict__ x1,
                             const float* __restrict__ x2, const float* __restrict__ x3,
                             const float* __restrict__ h0, const float* __restrict__ h1,
                             const float* __restrict__ h2, const float* __restrict__ h3,
                             unsigned short* __restrict__ Ap) {
    const int idx = blockIdx.x * 256 + threadIdx.x;   // 4096*192 total (8 k each)
    const int m = idx / 192, k8 = idx % 192;
    const int g = m & 3, r = m >> 2;
    const float* src;
    if (k8 < 64) {
        const float* a = (g & 2) ? ((g & 1) ? x3 : x2) : ((g & 1) ? x1 : x0);
        src = a + (size_t)r * IN_C + k8 * 8;
    } else {
        const float* a = (g & 2) ? ((g & 1) ? h3 : h2) : ((g & 1) ? h1 : h0);
        src = a + (size_t)r * OUT_C + (k8 - 64) * 8;
    }
    float4 v0 = reinterpret_cast<const float4*>(src)[0];
    float4 v1 = reinterpret_cast<const float4*>(src)[1];
    ushort4 o0, o1;
    o0.x = f2bf(v0.x); o0.y = f2bf(v0.y); o0.z = f2bf(v0.z); o0.w = f2bf(v0.w);
    o1.x = f2bf(v1.x); o1.y = f2bf(v1.y); o1.z = f2bf(v1.z); o1.w = f2bf(v1.w);
    ushort4* dst = reinterpret_cast<ushort4*>(Ap + (size_t)m * KTOT + k8 * 8);
    dst[0] = o0; dst[1] = o1;
}

// ---- fused MDLSTM as one 256x256-tile GEMM, 8 waves, 16x16x32 MFMA.
// r12 schedule (one barrier/K-tile) + ZERO-VALU addressing: offset-friendly
// LDS layout (A [P][kk][row256][64B] @0, B [dir][P][kk][row128][64B] @64K)
// so every frag read is ds_read_b128 off ONE base reg + imm offset, and the
// fully-unrolled K-loop folds j*128 into the global-load offset field.
__global__ __launch_bounds__(512, 2) void mdlstm_main(
    const unsigned short* __restrict__ Ap,    // [4096][1536] bf16
    const unsigned short* __restrict__ xT,    // [8192][512]  bf16
    const unsigned short* __restrict__ h0T,   // [8192][1024] bf16
    const unsigned short* __restrict__ h1T,   // [8192][1024] bf16
    const float* __restrict__ b_i, const float* __restrict__ b_f,
    const float* __restrict__ b_g, const float* __restrict__ b_o,
    const float* __restrict__ cp0, const float* __restrict__ cp1,
    const float* __restrict__ wsum,
    float* __restrict__ out)
{
    __shared__ __align__(16) unsigned char smem[131072];

    const int tid  = threadIdx.x;
    const int lane = tid & 63;
    const int wid  = tid >> 6;      // 0..7
    const int wm   = wid >> 2;      // 0..1 : A-half
    const int wn   = wid & 3;       // 0..3 : (dir = wn>>1, sample-half = wn&1)
    const int g4   = lane >> 4;
    const int l16  = lane & 15;

    const int by    = blockIdx.y;         // 0..15
    const int bcol  = blockIdx.x * 128;   // sample base
    const int browM = by * 256;           // A'-row base

    f32x4 acc[8][4];
#pragma unroll
    for (int mf = 0; mf < 8; ++mf)
#pragma unroll
        for (int nf = 0; nf < 4; ++nf)
            acc[mf][nf] = (f32x4){0.f, 0.f, 0.f, 0.f};

    // ---- per-thread LDS read bases (swz = ((l16>>1)&3), mf/nf-independent) ----
    const int swzlo = (g4 * 16) ^ (((l16 >> 1) & 3) << 4);
    unsigned char* const aBase = smem + wm * 8192 + l16 * 64 + swzlo;
    unsigned char* const bBase = smem + 65536 + (wn >> 1) * 32768 + (wn & 1) * 4096
                                 + l16 * 64 + swzlo;

    // ---- per-thread staging constants ----
    const int srow = tid >> 2;            // (tid*16)>>6 : 0..127
    const int skb  = (tid * 16) & 63;

    // A sources: issue c -> global row (c&1)*128 + srow, kk-half c>>1
    const char* srcA0; const char* srcA1; const char* srcA2; const char* srcA3;
    {
        auto mk = [&](int c) -> const char* {
            const int row = (c & 1) * 128 + srow;
            const int kk  = c >> 1;
            return (const char*)Ap + ((size_t)(browM + row) * KTOT + kk * 32) * 2
                   + (skb ^ (((row >> 1) & 3) << 4));
        };
        srcA0 = mk(0); srcA1 = mk(1); srcA2 = mk(2); srcA3 = mk(3);
    }
    // B sources: row srow (0..127), kk-half c
    const int swB = ((srow >> 1) & 3) << 4;
    const char* srcBx0 = (const char*)xT  + ((size_t)(bcol + srow) * IN_C)  * 2 + (skb ^ swB);
    const char* srcBx1 = srcBx0 + 64;
    const char* srcBh00 = (const char*)h0T + ((size_t)(bcol + srow) * OUT_C) * 2 + (skb ^ swB);
    const char* srcBh01 = srcBh00 + 64;
    const char* srcBh10 = (const char*)h1T + ((size_t)(bcol + srow) * OUT_C) * 2 + (skb ^ swB);
    const char* srcBh11 = srcBh10 + 64;

    // stage A tile j into buffer P (4 x 16B per thread, linear dest)
    auto stage_A = [&](int P, int j) {
        __builtin_amdgcn_global_load_lds((const unsigned int*)(srcA0 + j * 128),
            (unsigned int*)(smem + P * 32768 +     0 + tid * 16), 16, 0, 0);
        __builtin_amdgcn_global_load_lds((const unsigned int*)(srcA1 + j * 128),
            (unsigned int*)(smem + P * 32768 +  8192 + tid * 16), 16, 0, 0);
        __builtin_amdgcn_global_load_lds((const unsigned int*)(srcA2 + j * 128),
            (unsigned int*)(smem + P * 32768 + 16384 + tid * 16), 16, 0, 0);
        __builtin_amdgcn_global_load_lds((const unsigned int*)(srcA3 + j * 128),
            (unsigned int*)(smem + P * 32768 + 24576 + tid * 16), 16, 0, 0);
    };
    // stage B tile j2, dir d into buffer P (2 x 16B per thread)
    auto stage_B = [&](int P, int d, int j2) {
        const char* s0 = (j2 < 8) ? (srcBx0 + j2 * 128) : ((d ? srcBh10 : srcBh00) + (j2 - 8) * 128);
        const char* s1 = (j2 < 8) ? (srcBx1 + j2 * 128) : ((d ? srcBh11 : srcBh01) + (j2 - 8) * 128);
        __builtin_amdgcn_global_load_lds((const unsigned int*)s0,
            (unsigned int*)(smem + 65536 + d * 32768 + P * 16384 +    0 + tid * 16), 16, 0, 0);
        __builtin_amdgcn_global_load_lds((const unsigned int*)s1,
            (unsigned int*)(smem + 65536 + d * 32768 + P * 16384 + 8192 + tid * 16), 16, 0, 0);
    };

    auto fragA = [&](int P, int mf, int kk) -> bf16x8 {
        return *reinterpret_cast<const bf16x8*>(aBase + P * 32768 + kk * 16384 + mf * 1024);
    };
    auto fragB = [&](int P, int nf, int kk) -> bf16x8 {
        return *reinterpret_cast<const bf16x8*>(bBase + P * 16384 + kk * 8192 + nf * 1024);
    };

    bf16x8 aF[2][2];   // current cluster's A pair
    bf16x8 bF[4][2];   // current tile's B frags

    auto cluster = [&](int M) {
        __builtin_amdgcn_s_setprio(1);
#pragma unroll
        for (int kk = 0; kk < 2; ++kk)
#pragma unroll
            for (int mi = 0; mi < 2; ++mi)
#pragma unroll
                for (int nf = 0; nf < 4; ++nf)
                    acc[M + mi][nf] = __builtin_amdgcn_mfma_f32_16x16x32_bf16(
                        aF[mi][kk], bF[nf][kk], acc[M + mi][nf], 0, 0, 0);
        __builtin_amdgcn_s_setprio(0);
    };
    auto loadA = [&](int P, int mf) {
#pragma unroll
        for (int kk = 0; kk < 2; ++kk) { aF[0][kk] = fragA(P, mf, kk); aF[1][kk] = fragA(P, mf + 1, kk); }
    };
    auto loadB = [&](int P) {
#pragma unroll
        for (int nf = 0; nf < 4; ++nf)
#pragma unroll
            for (int kk = 0; kk < 2; ++kk) bF[nf][kk] = fragB(P, nf, kk);
    };

    // ---------------- prologue: stage tile 0 ----------------
    stage_A(0, 0);
    stage_B(0, 0, 0); stage_B(0, 1, 0);
    SFENCE(); VM0(); SFENCE();
    SBAR();

    // ---------------- main loop: 24 K-tiles, FULLY UNROLLED ----------------
#pragma unroll
    for (int j = 0; j < 24; ++j) {
        const int P = j & 1, PN = P ^ 1;
        const bool st = (j < 23);
        // chunk 1: B frags (8) + A mf0,1 ; MFMA mf0,1
        loadB(P);
        loadA(P, 0);
        cluster(0);
        // chunk 2: A mf2,3 ; stage A(j+1) ; MFMA mf2,3
        loadA(P, 2);
        if (st) stage_A(PN, j + 1);
        cluster(2);
        // chunk 3: A mf4,5 ; stage B(j+1) ; MFMA mf4,5
        loadA(P, 4);
        if (st) { stage_B(PN, 0, j + 1); stage_B(PN, 1, j + 1); }
        cluster(4);
        // chunk 4: A mf6,7 ; MFMA mf6,7 ; drain ; barrier
        loadA(P, 6);
        cluster(6);
        SFENCE(); VM0(); SFENCE();
        SBAR();
    }

    // ---------------- epilogue: lane-local gates; LDS exchange for dir combine ----
    const float w0 = wsum[0], w1 = wsum[1];
    const int   d  = wn >> 1;
    const float* cp = d ? cp1 : cp0;
    const float wd  = d ? w1 : w0;

    float rc[8][4], rh[8][4];
#pragma unroll
    for (int mf = 0; mf < 8; ++mf) {
        const int orow = by * 64 + wm * 32 + mf * 4 + g4;
        const float bi = b_i[orow], bff = b_f[orow], bg = b_g[orow], bo = b_o[orow];
#pragma unroll
        for (int nf = 0; nf < 4; ++nf) {
            const int scol = bcol + (wn & 1) * 64 + nf * 16 + l16;
            float i_ = sigmoid_f(acc[mf][nf][0] + bi);
            float f_ = sigmoid_f(acc[mf][nf][1] + bff);
            float g_ = tanh_f  (acc[mf][nf][2] + bg);
            float o_ = sigmoid_f(acc[mf][nf][3] + bo);
            float cc = f_ * cp[(size_t)orow * NSAMP + scol] + i_ * g_;
            float hh = o_ * tanh_f(cc);
            rc[mf][nf] = wd * cc;
            rh[mf][nf] = wd * hh;
        }
    }

    float* ex = (float*)smem;
    const int rbase = (wm * 2 + (wn & 1)) * 4096;   // 16KB region per (wm, sample-half)
    if (d == 1) {
#pragma unroll
        for (int mf = 0; mf < 8; ++mf)
#pragma unroll
            for (int nf = 0; nf < 4; ++nf) {
                const int slot = rbase + (mf * 4 + nf) * 64 + lane;
                ex[slot]        = rc[mf][nf];
                ex[slot + 2048] = rh[mf][nf];
            }
    }
    SBAR();
    if (d == 0) {
#pragma unroll
        for (int mf = 0; mf < 8; ++mf) {
            const int orow = by * 64 + wm * 32 + mf * 4 + g4;
#pragma unroll
            for (int nf = 0; nf < 4; ++nf) {
                const int scol = bcol + (wn & 1) * 64 + nf * 16 + l16;
                const int slot = rbase + (mf * 4 + nf) * 64 + lane;
                out[(size_t)orow * NSAMP + scol] = rc[mf][nf] + ex[slot];
                out[(size_t)OUT_C * NSAMP + (size_t)orow * NSAMP + scol] = rh[mf][nf] + ex[slot + 2048];
            }
        }
    }
}

extern "C" void kernel_launch(void* const* d_in, const int* in_sizes, int n_in,
                              void* d_out, int out_size, void* d_ws, size_t ws_size,
                              hipStream_t stream) {
    (void)in_sizes; (void)n_in; (void)out_size; (void)ws_size;

    const float* x    = (const float*)d_in[0];
    const float* cp0  = (const float*)d_in[1];
    const float* hp0  = (const float*)d_in[2];
    const float* cp1  = (const float*)d_in[3];
    const float* hp1  = (const float*)d_in[4];
    const float* b_i  = (const float*)d_in[13];
    const float* b_f  = (const float*)d_in[14];
    const float* b_g  = (const float*)d_in[15];
    const float* b_o  = (const float*)d_in[16];
    const float* wsum = (const float*)d_in[17];
    float* out = (float*)d_out;

    // workspace: xT 8MB @0, h0T 16MB @8M, h1T 16MB @24M, Ap 12MB @40M
    char* ws = (char*)d_ws;
    unsigned short* xT  = (unsigned short*)(ws);
    unsigned short* h0T = (unsigned short*)(ws + (size_t)8  * 1024 * 1024);
    unsigned short* h1T = (unsigned short*)(ws + (size_t)24 * 1024 * 1024);
    unsigned short* Ap  = (unsigned short*)(ws + (size_t)40 * 1024 * 1024);

    dim3 tb(32, 8);
    tcvt_kernel<<<dim3(NSAMP / 32, IN_C  / 32), tb, 0, stream>>>(x,   xT,  IN_C,  NSAMP);
    tcvt_kernel<<<dim3(NSAMP / 32, OUT_C / 32), tb, 0, stream>>>(hp0, h0T, OUT_C, NSAMP);
    tcvt_kernel<<<dim3(NSAMP / 32, OUT_C / 32), tb, 0, stream>>>(hp1, h1T, OUT_C, NSAMP);

    packA_kernel<<<(4096 * 192) / 256, 256, 0, stream>>>(
        (const float*)d_in[5], (const float*)d_in[6], (const float*)d_in[7], (const float*)d_in[8],
        (const float*)d_in[9], (const float*)d_in[10], (const float*)d_in[11], (const float*)d_in[12],
        Ap);

    mdlstm_main<<<dim3(NSAMP / 128, OUT_C / 64), 512, 0, stream>>>(
        Ap, xT, h0T, h1T, b_i, b_f, b_g, b_o, cp0, cp1, wsum, out);
}

// Round 18
// 234.753 us; speedup vs baseline: 1.9412x; 1.0075x over previous
//
#include <hip/hip_runtime.h>
#include <cstdint>
#include <cstddef>

#define IN_C  512
#define OUT_C 1024
#define NSAMP 8192
#define KTOT  1536

typedef __bf16 bf16x8 __attribute__((ext_vector_type(8)));
typedef float  f32x4  __attribute__((ext_vector_type(4)));

#define SBAR()   __builtin_amdgcn_s_barrier()
#define SFENCE() __builtin_amdgcn_sched_barrier(0)
#define VM4()    asm volatile("s_waitcnt vmcnt(4)")
#define VM0()    asm volatile("s_waitcnt vmcnt(0)")

__device__ __forceinline__ unsigned short f2bf(float f) {
    unsigned int u = __float_as_uint(f);
    u += 0x7FFFu + ((u >> 16) & 1u);   // round-to-nearest-even
    return (unsigned short)(u >> 16);
}
__device__ __forceinline__ float sigmoid_f(float x) { return 1.0f / (1.0f + __expf(-x)); }
__device__ __forceinline__ float tanh_f(float x) {
    float e = __expf(2.0f * x);
    return 1.0f - 2.0f / (e + 1.0f);
}

// ---- transpose + f32->bf16: in (R x C) row-major -> out (C x R) row-major ----
__global__ void tcvt_kernel(const float* __restrict__ in, unsigned short* __restrict__ out,
                            int R, int C) {
    __shared__ float t[32][33];
    const int tx = threadIdx.x, ty = threadIdx.y;
    const int c0 = blockIdx.x * 32, r0 = blockIdx.y * 32;
#pragma unroll
    for (int i = 0; i < 4; ++i)
        t[ty + i * 8][tx] = in[(size_t)(r0 + ty + i * 8) * C + (c0 + tx)];
    __syncthreads();
#pragma unroll
    for (int i = 0; i < 4; ++i)
        out[(size_t)(c0 + ty + i * 8) * R + (r0 + tx)] = f2bf(t[tx][ty + i * 8]);
}

// ---- pack A'[4096][1536]: row m = out_row*4 + gate; k<512 from wx_g, else wh_g ----
__global__ void packA_kernel(const float* __restrict__ x0, const float* __restrict__ x1,
                             const float* __restrict__ x2, const float* __restrict__ x3,
                             const float* __restrict__ h0, const float* __restrict__ h1,
                             const float* __restrict__ h2, const float* __restrict__ h3,
                             unsigned short* __restrict__ Ap) {
    const int idx = blockIdx.x * 256 + threadIdx.x;   // 4096*192 total (8 k each)
    const int m = idx / 192, k8 = idx % 192;
    const int g = m & 3, r = m >> 2;
    const float* src;
    if (k8 < 64) {
        const float* a = (g & 2) ? ((g & 1) ? x3 : x2) : ((g & 1) ? x1 : x0);
        src = a + (size_t)r * IN_C + k8 * 8;
    } else {
        const float* a = (g & 2) ? ((g & 1) ? h3 : h2) : ((g & 1) ? h1 : h0);
        src = a + (size_t)r * OUT_C + (k8 - 64) * 8;
    }
    float4 v0 = reinterpret_cast<const float4*>(src)[0];
    float4 v1 = reinterpret_cast<const float4*>(src)[1];
    ushort4 o0, o1;
    o0.x = f2bf(v0.x); o0.y = f2bf(v0.y); o0.z = f2bf(v0.z); o0.w = f2bf(v0.w);
    o1.x = f2bf(v1.x); o1.y = f2bf(v1.y); o1.z = f2bf(v1.z); o1.w = f2bf(v1.w);
    ushort4* dst = reinterpret_cast<ushort4*>(Ap + (size_t)m * KTOT + k8 * 8);
    dst[0] = o0; dst[1] = o1;
}

// ---- fused MDLSTM as one 256x256-tile GEMM, 8 waves, 16x16x32 MFMA.
// r17 schedule + DEPTH-2 B prefetch: B(j+2) staged into the CURRENT buffer's
// B region (dead after loadB), so the steady-state tile-end wait is a counted
// vmcnt(4) (A(j+1) only) instead of a full drain.
__global__ __launch_bounds__(512, 2) void mdlstm_main(
    const unsigned short* __restrict__ Ap,    // [4096][1536] bf16
    const unsigned short* __restrict__ xT,    // [8192][512]  bf16
    const unsigned short* __restrict__ h0T,   // [8192][1024] bf16
    const unsigned short* __restrict__ h1T,   // [8192][1024] bf16
    const float* __restrict__ b_i, const float* __restrict__ b_f,
    const float* __restrict__ b_g, const float* __restrict__ b_o,
    const float* __restrict__ cp0, const float* __restrict__ cp1,
    const float* __restrict__ wsum,
    float* __restrict__ out)
{
    __shared__ __align__(16) unsigned char smem[131072];

    const int tid  = threadIdx.x;
    const int lane = tid & 63;
    const int wid  = tid >> 6;      // 0..7
    const int wm   = wid >> 2;      // 0..1 : A-half
    const int wn   = wid & 3;       // 0..3 : (dir = wn>>1, sample-half = wn&1)
    const int g4   = lane >> 4;
    const int l16  = lane & 15;

    const int by    = blockIdx.y;         // 0..15
    const int bcol  = blockIdx.x * 128;   // sample base
    const int browM = by * 256;           // A'-row base

    f32x4 acc[8][4];
#pragma unroll
    for (int mf = 0; mf < 8; ++mf)
#pragma unroll
        for (int nf = 0; nf < 4; ++nf)
            acc[mf][nf] = (f32x4){0.f, 0.f, 0.f, 0.f};

    // ---- per-thread LDS read bases (swz = ((l16>>1)&3), mf/nf-independent) ----
    const int swzlo = (g4 * 16) ^ (((l16 >> 1) & 3) << 4);
    unsigned char* const aBase = smem + wm * 8192 + l16 * 64 + swzlo;
    unsigned char* const bBase = smem + 65536 + (wn >> 1) * 32768 + (wn & 1) * 4096
                                 + l16 * 64 + swzlo;

    // ---- per-thread staging constants ----
    const int srow = tid >> 2;            // 0..127
    const int skb  = (tid * 16) & 63;

    const char* srcA0; const char* srcA1; const char* srcA2; const char* srcA3;
    {
        auto mk = [&](int c) -> const char* {
            const int row = (c & 1) * 128 + srow;
            const int kk  = c >> 1;
            return (const char*)Ap + ((size_t)(browM + row) * KTOT + kk * 32) * 2
                   + (skb ^ (((row >> 1) & 3) << 4));
        };
        srcA0 = mk(0); srcA1 = mk(1); srcA2 = mk(2); srcA3 = mk(3);
    }
    const int swB = ((srow >> 1) & 3) << 4;
    const char* srcBx0 = (const char*)xT  + ((size_t)(bcol + srow) * IN_C)  * 2 + (skb ^ swB);
    const char* srcBx1 = srcBx0 + 64;
    const char* srcBh00 = (const char*)h0T + ((size_t)(bcol + srow) * OUT_C) * 2 + (skb ^ swB);
    const char* srcBh01 = srcBh00 + 64;
    const char* srcBh10 = (const char*)h1T + ((size_t)(bcol + srow) * OUT_C) * 2 + (skb ^ swB);
    const char* srcBh11 = srcBh10 + 64;

    auto stage_A = [&](int P, int j) {
        __builtin_amdgcn_global_load_lds((const unsigned int*)(srcA0 + j * 128),
            (unsigned int*)(smem + P * 32768 +     0 + tid * 16), 16, 0, 0);
        __builtin_amdgcn_global_load_lds((const unsigned int*)(srcA1 + j * 128),
            (unsigned int*)(smem + P * 32768 +  8192 + tid * 16), 16, 0, 0);
        __builtin_amdgcn_global_load_lds((const unsigned int*)(srcA2 + j * 128),
            (unsigned int*)(smem + P * 32768 + 16384 + tid * 16), 16, 0, 0);
        __builtin_amdgcn_global_load_lds((const unsigned int*)(srcA3 + j * 128),
            (unsigned int*)(smem + P * 32768 + 24576 + tid * 16), 16, 0, 0);
    };
    auto stage_B = [&](int P, int d, int j2) {
        const char* s0 = (j2 < 8) ? (srcBx0 + j2 * 128) : ((d ? srcBh10 : srcBh00) + (j2 - 8) * 128);
        const char* s1 = (j2 < 8) ? (srcBx1 + j2 * 128) : ((d ? srcBh11 : srcBh01) + (j2 - 8) * 128);
        __builtin_amdgcn_global_load_lds((const unsigned int*)s0,
            (unsigned int*)(smem + 65536 + d * 32768 + P * 16384 +    0 + tid * 16), 16, 0, 0);
        __builtin_amdgcn_global_load_lds((const unsigned int*)s1,
            (unsigned int*)(smem + 65536 + d * 32768 + P * 16384 + 8192 + tid * 16), 16, 0, 0);
    };

    auto fragA = [&](int P, int mf, int kk) -> bf16x8 {
        return *reinterpret_cast<const bf16x8*>(aBase + P * 32768 + kk * 16384 + mf * 1024);
    };
    auto fragB = [&](int P, int nf, int kk) -> bf16x8 {
        return *reinterpret_cast<const bf16x8*>(bBase + P * 16384 + kk * 8192 + nf * 1024);
    };

    bf16x8 aF[2][2];
    bf16x8 bF[4][2];

    auto cluster = [&](int M) {
        __builtin_amdgcn_s_setprio(1);
#pragma unroll
        for (int kk = 0; kk < 2; ++kk)
#pragma unroll
            for (int mi = 0; mi < 2; ++mi)
#pragma unroll
                for (int nf = 0; nf < 4; ++nf)
                    acc[M + mi][nf] = __builtin_amdgcn_mfma_f32_16x16x32_bf16(
                        aF[mi][kk], bF[nf][kk], acc[M + mi][nf], 0, 0, 0);
        __builtin_amdgcn_s_setprio(0);
    };
    auto loadA = [&](int P, int mf) {
#pragma unroll
        for (int kk = 0; kk < 2; ++kk) { aF[0][kk] = fragA(P, mf, kk); aF[1][kk] = fragA(P, mf + 1, kk); }
    };
    auto loadB = [&](int P) {
#pragma unroll
        for (int nf = 0; nf < 4; ++nf)
#pragma unroll
            for (int kk = 0; kk < 2; ++kk) bF[nf][kk] = fragB(P, nf, kk);
    };

    // ---------------- prologue: A(0),B(0) -> buf0 ; B(1) -> buf1 ----------------
    stage_A(0, 0);
    stage_B(0, 0, 0); stage_B(0, 1, 0);
    stage_B(1, 0, 1); stage_B(1, 1, 1);
    SFENCE(); VM4(); SFENCE();            // A(0),B(0) landed; B(1) may fly
    SBAR();

    // ---------------- main loop: 24 K-tiles, fully unrolled ----------------
#pragma unroll
    for (int j = 0; j < 24; ++j) {
        const int P = j & 1, PN = P ^ 1;
        // chunk 1: B frags + A mf0,1 ; stage A(j+1) -> PN ; MFMA mf0,1
        loadB(P);
        loadA(P, 0);
        if (j < 23) stage_A(PN, j + 1);
        cluster(0);
        // chunk 2: A mf2,3 ; stage B(j+2) -> P (B region dead after loadB) ; MFMA mf2,3
        loadA(P, 2);
        if (j < 22) { stage_B(P, 0, j + 2); stage_B(P, 1, j + 2); }
        cluster(2);
        // chunk 3: A mf4,5 ; MFMA mf4,5
        loadA(P, 4);
        cluster(4);
        // chunk 4: A mf6,7 ; MFMA mf6,7 ; counted wait ; barrier
        loadA(P, 6);
        cluster(6);
        SFENCE();
        if (j < 22) { VM4(); } else { VM0(); }
        SFENCE();
        SBAR();
    }

    // ---------------- epilogue: lane-local gates; LDS exchange for dir combine ----
    const float w0 = wsum[0], w1 = wsum[1];
    const int   d  = wn >> 1;
    const float* cp = d ? cp1 : cp0;
    const float wd  = d ? w1 : w0;

    float rc[8][4], rh[8][4];
#pragma unroll
    for (int mf = 0; mf < 8; ++mf) {
        const int orow = by * 64 + wm * 32 + mf * 4 + g4;
        const float bi = b_i[orow], bff = b_f[orow], bg = b_g[orow], bo = b_o[orow];
#pragma unroll
        for (int nf = 0; nf < 4; ++nf) {
            const int scol = bcol + (wn & 1) * 64 + nf * 16 + l16;
            float i_ = sigmoid_f(acc[mf][nf][0] + bi);
            float f_ = sigmoid_f(acc[mf][nf][1] + bff);
            float g_ = tanh_f  (acc[mf][nf][2] + bg);
            float o_ = sigmoid_f(acc[mf][nf][3] + bo);
            float cc = f_ * cp[(size_t)orow * NSAMP + scol] + i_ * g_;
            float hh = o_ * tanh_f(cc);
            rc[mf][nf] = wd * cc;
            rh[mf][nf] = wd * hh;
        }
    }

    float* ex = (float*)smem;
    const int rbase = (wm * 2 + (wn & 1)) * 4096;   // 16KB region per (wm, sample-half)
    if (d == 1) {
#pragma unroll
        for (int mf = 0; mf < 8; ++mf)
#pragma unroll
            for (int nf = 0; nf < 4; ++nf) {
                const int slot = rbase + (mf * 4 + nf) * 64 + lane;
                ex[slot]        = rc[mf][nf];
                ex[slot + 2048] = rh[mf][nf];
            }
    }
    SBAR();
    if (d == 0) {
#pragma unroll
        for (int mf = 0; mf < 8; ++mf) {
            const int orow = by * 64 + wm * 32 + mf * 4 + g4;
#pragma unroll
            for (int nf = 0; nf < 4; ++nf) {
                const int scol = bcol + (wn & 1) * 64 + nf * 16 + l16;
                const int slot = rbase + (mf * 4 + nf) * 64 + lane;
                out[(size_t)orow * NSAMP + scol] = rc[mf][nf] + ex[slot];
                out[(size_t)OUT_C * NSAMP + (size_t)orow * NSAMP + scol] = rh[mf][nf] + ex[slot + 2048];
            }
        }
    }
}

extern "C" void kernel_launch(void* const* d_in, const int* in_sizes, int n_in,
                              void* d_out, int out_size, void* d_ws, size_t ws_size,
                              hipStream_t stream) {
    (void)in_sizes; (void)n_in; (void)out_size; (void)ws_size;

    const float* x    = (const float*)d_in[0];
    const float* cp0  = (const float*)d_in[1];
    const float* hp0  = (const float*)d_in[2];
    const float* cp1  = (const float*)d_in[3];
    const float* hp1  = (const float*)d_in[4];
    const float* b_i  = (const float*)d_in[13];
    const float* b_f  = (const float*)d_in[14];
    const float* b_g  = (const float*)d_in[15];
    const float* b_o  = (const float*)d_in[16];
    const float* wsum = (const float*)d_in[17];
    float* out = (float*)d_out;

    // workspace: xT 8MB @0, h0T 16MB @8M, h1T 16MB @24M, Ap 12MB @40M
    char* ws = (char*)d_ws;
    unsigned short* xT  = (unsigned short*)(ws);
    unsigned short* h0T = (unsigned short*)(ws + (size_t)8  * 1024 * 1024);
    unsigned short* h1T = (unsigned short*)(ws + (size_t)24 * 1024 * 1024);
    unsigned short* Ap  = (unsigned short*)(ws + (size_t)40 * 1024 * 1024);

    dim3 tb(32, 8);
    tcvt_kernel<<<dim3(NSAMP / 32, IN_C  / 32), tb, 0, stream>>>(x,   xT,  IN_C,  NSAMP);
    tcvt_kernel<<<dim3(NSAMP / 32, OUT_C / 32), tb, 0, stream>>>(hp0, h0T, OUT_C, NSAMP);
    tcvt_kernel<<<dim3(NSAMP / 32, OUT_C / 32), tb, 0, stream>>>(hp1, h1T, OUT_C, NSAMP);

    packA_kernel<<<(4096 * 192) / 256, 256, 0, stream>>>(
        (const float*)d_in[5], (const float*)d_in[6], (const float*)d_in[7], (const float*)d_in[8],
        (const float*)d_in[9], (const float*)d_in[10], (const float*)d_in[11], (const float*)d_in[12],
        Ap);

    mdlstm_main<<<dim3(NSAMP / 128, OUT_C / 64), 512, 0, stream>>>(
        Ap, xT, h0T, h1T, b_i, b_f, b_g, b_o, cp0, cp1, wsum, out);
}

// Round 20
// 231.341 us; speedup vs baseline: 1.9698x; 1.0148x over previous
//
#include <hip/hip_runtime.h>
#include <cstdint>
#include <cstddef>

#define IN_C  512
#define OUT_C 1024
#define NSAMP 8192
#define KTOT  1536

typedef __bf16 bf16x8 __attribute__((ext_vector_type(8)));
typedef float  f32x4  __attribute__((ext_vector_type(4)));

#define SBAR()   __builtin_amdgcn_s_barrier()
#define SFENCE() __builtin_amdgcn_sched_barrier(0)
#define VM4()    asm volatile("s_waitcnt vmcnt(4)")
#define VM0()    asm volatile("s_waitcnt vmcnt(0)")

__device__ __forceinline__ unsigned short f2bf(float f) {
    unsigned int u = __float_as_uint(f);
    u += 0x7FFFu + ((u >> 16) & 1u);   // round-to-nearest-even
    return (unsigned short)(u >> 16);
}
__device__ __forceinline__ float sigmoid_f(float x) { return 1.0f / (1.0f + __expf(-x)); }
__device__ __forceinline__ float tanh_f(float x) {
    float e = __expf(2.0f * x);
    return 1.0f - 2.0f / (e + 1.0f);
}

// ---- fused transpose + f32->bf16 for x, h_prev0, h_prev1 (one launch) ----
// in (R x NSAMP) row-major -> out (NSAMP x R) row-major
__global__ void tcvt3_kernel(const float* __restrict__ x,
                             const float* __restrict__ h0,
                             const float* __restrict__ h1,
                             unsigned short* __restrict__ xT,
                             unsigned short* __restrict__ h0T,
                             unsigned short* __restrict__ h1T) {
    __shared__ float t[32][33];
    const int tx = threadIdx.x, ty = threadIdx.y;
    const int byy = blockIdx.y;

    const float* in; unsigned short* out; int R; int r0;
    if (byy < 16)      { in = x;  out = xT;  R = IN_C;  r0 = byy * 32; }
    else if (byy < 48) { in = h0; out = h0T; R = OUT_C; r0 = (byy - 16) * 32; }
    else               { in = h1; out = h1T; R = OUT_C; r0 = (byy - 48) * 32; }

    const int c0 = blockIdx.x * 32;
#pragma unroll
    for (int i = 0; i < 4; ++i)
        t[ty + i * 8][tx] = in[(size_t)(r0 + ty + i * 8) * NSAMP + (c0 + tx)];
    __syncthreads();
#pragma unroll
    for (int i = 0; i < 4; ++i)
        out[(size_t)(c0 + ty + i * 8) * R + (r0 + tx)] = f2bf(t[tx][ty + i * 8]);
}

// ---- pack A'[4096][1536]: row m = out_row*4 + gate; k<512 from wx_g, else wh_g ----
__global__ void packA_kernel(const float* __restrict__ x0, const float* __restrict__ x1,
                             const float* __restrict__ x2, const float* __restrict__ x3,
                             const float* __restrict__ h0, const float* __restrict__ h1,
                             const float* __restrict__ h2, const float* __restrict__ h3,
                             unsigned short* __restrict__ Ap) {
    const int idx = blockIdx.x * 256 + threadIdx.x;   // 4096*192 total (8 k each)
    const int m = idx / 192, k8 = idx % 192;
    const int g = m & 3, r = m >> 2;
    const float* src;
    if (k8 < 64) {
        const float* a = (g & 2) ? ((g & 1) ? x3 : x2) : ((g & 1) ? x1 : x0);
        src = a + (size_t)r * IN_C + k8 * 8;
    } else {
        const float* a = (g & 2) ? ((g & 1) ? h3 : h2) : ((g & 1) ? h1 : h0);
        src = a + (size_t)r * OUT_C + (k8 - 64) * 8;
    }
    float4 v0 = reinterpret_cast<const float4*>(src)[0];
    float4 v1 = reinterpret_cast<const float4*>(src)[1];
    ushort4 o0, o1;
    o0.x = f2bf(v0.x); o0.y = f2bf(v0.y); o0.z = f2bf(v0.z); o0.w = f2bf(v0.w);
    o1.x = f2bf(v1.x); o1.y = f2bf(v1.y); o1.z = f2bf(v1.z); o1.w = f2bf(v1.w);
    ushort4* dst = reinterpret_cast<ushort4*>(Ap + (size_t)m * KTOT + k8 * 8);
    dst[0] = o0; dst[1] = o1;
}

// ---- fused MDLSTM as one 256x256-tile GEMM, 8 waves, 16x16x32 MFMA.
// r18 (verified best): one barrier/K-tile, zero-VALU addressing (offset-
// friendly LDS layout + fully-unrolled K-loop), depth-2 B prefetch with
// counted vmcnt(4).
__global__ __launch_bounds__(512, 2) void mdlstm_main(
    const unsigned short* __restrict__ Ap,    // [4096][1536] bf16
    const unsigned short* __restrict__ xT,    // [8192][512]  bf16
    const unsigned short* __restrict__ h0T,   // [8192][1024] bf16
    const unsigned short* __restrict__ h1T,   // [8192][1024] bf16
    const float* __restrict__ b_i, const float* __restrict__ b_f,
    const float* __restrict__ b_g, const float* __restrict__ b_o,
    const float* __restrict__ cp0, const float* __restrict__ cp1,
    const float* __restrict__ wsum,
    float* __restrict__ out)
{
    __shared__ __align__(16) unsigned char smem[131072];

    const int tid  = threadIdx.x;
    const int lane = tid & 63;
    const int wid  = tid >> 6;      // 0..7
    const int wm   = wid >> 2;      // 0..1 : A-half
    const int wn   = wid & 3;       // 0..3 : (dir = wn>>1, sample-half = wn&1)
    const int g4   = lane >> 4;
    const int l16  = lane & 15;

    const int by    = blockIdx.y;         // 0..15
    const int bcol  = blockIdx.x * 128;   // sample base
    const int browM = by * 256;           // A'-row base

    f32x4 acc[8][4];
#pragma unroll
    for (int mf = 0; mf < 8; ++mf)
#pragma unroll
        for (int nf = 0; nf < 4; ++nf)
            acc[mf][nf] = (f32x4){0.f, 0.f, 0.f, 0.f};

    // ---- per-thread LDS read bases (swz = ((l16>>1)&3), mf/nf-independent) ----
    const int swzlo = (g4 * 16) ^ (((l16 >> 1) & 3) << 4);
    unsigned char* const aBase = smem + wm * 8192 + l16 * 64 + swzlo;
    unsigned char* const bBase = smem + 65536 + (wn >> 1) * 32768 + (wn & 1) * 4096
                                 + l16 * 64 + swzlo;

    // ---- per-thread staging constants ----
    const int srow = tid >> 2;            // 0..127
    const int skb  = (tid * 16) & 63;

    const char* srcA0; const char* srcA1; const char* srcA2; const char* srcA3;
    {
        auto mk = [&](int c) -> const char* {
            const int row = (c & 1) * 128 + srow;
            const int kk  = c >> 1;
            return (const char*)Ap + ((size_t)(browM + row) * KTOT + kk * 32) * 2
                   + (skb ^ (((row >> 1) & 3) << 4));
        };
        srcA0 = mk(0); srcA1 = mk(1); srcA2 = mk(2); srcA3 = mk(3);
    }
    const int swB = ((srow >> 1) & 3) << 4;
    const char* srcBx0 = (const char*)xT  + ((size_t)(bcol + srow) * IN_C)  * 2 + (skb ^ swB);
    const char* srcBx1 = srcBx0 + 64;
    const char* srcBh00 = (const char*)h0T + ((size_t)(bcol + srow) * OUT_C) * 2 + (skb ^ swB);
    const char* srcBh01 = srcBh00 + 64;
    const char* srcBh10 = (const char*)h1T + ((size_t)(bcol + srow) * OUT_C) * 2 + (skb ^ swB);
    const char* srcBh11 = srcBh10 + 64;

    auto stage_A = [&](int P, int j) {
        __builtin_amdgcn_global_load_lds((const unsigned int*)(srcA0 + j * 128),
            (unsigned int*)(smem + P * 32768 +     0 + tid * 16), 16, 0, 0);
        __builtin_amdgcn_global_load_lds((const unsigned int*)(srcA1 + j * 128),
            (unsigned int*)(smem + P * 32768 +  8192 + tid * 16), 16, 0, 0);
        __builtin_amdgcn_global_load_lds((const unsigned int*)(srcA2 + j * 128),
            (unsigned int*)(smem + P * 32768 + 16384 + tid * 16), 16, 0, 0);
        __builtin_amdgcn_global_load_lds((const unsigned int*)(srcA3 + j * 128),
            (unsigned int*)(smem + P * 32768 + 24576 + tid * 16), 16, 0, 0);
    };
    auto stage_B = [&](int P, int d, int j2) {
        const char* s0 = (j2 < 8) ? (srcBx0 + j2 * 128) : ((d ? srcBh10 : srcBh00) + (j2 - 8) * 128);
        const char* s1 = (j2 < 8) ? (srcBx1 + j2 * 128) : ((d ? srcBh11 : srcBh01) + (j2 - 8) * 128);
        __builtin_amdgcn_global_load_lds((const unsigned int*)s0,
            (unsigned int*)(smem + 65536 + d * 32768 + P * 16384 +    0 + tid * 16), 16, 0, 0);
        __builtin_amdgcn_global_load_lds((const unsigned int*)s1,
            (unsigned int*)(smem + 65536 + d * 32768 + P * 16384 + 8192 + tid * 16), 16, 0, 0);
    };

    auto fragA = [&](int P, int mf, int kk) -> bf16x8 {
        return *reinterpret_cast<const bf16x8*>(aBase + P * 32768 + kk * 16384 + mf * 1024);
    };
    auto fragB = [&](int P, int nf, int kk) -> bf16x8 {
        return *reinterpret_cast<const bf16x8*>(bBase + P * 16384 + kk * 8192 + nf * 1024);
    };

    bf16x8 aF[2][2];
    bf16x8 bF[4][2];

    auto cluster = [&](int M) {
        __builtin_amdgcn_s_setprio(1);
#pragma unroll
        for (int kk = 0; kk < 2; ++kk)
#pragma unroll
            for (int mi = 0; mi < 2; ++mi)
#pragma unroll
                for (int nf = 0; nf < 4; ++nf)
                    acc[M + mi][nf] = __builtin_amdgcn_mfma_f32_16x16x32_bf16(
                        aF[mi][kk], bF[nf][kk], acc[M + mi][nf], 0, 0, 0);
        __builtin_amdgcn_s_setprio(0);
    };
    auto loadA = [&](int P, int mf) {
#pragma unroll
        for (int kk = 0; kk < 2; ++kk) { aF[0][kk] = fragA(P, mf, kk); aF[1][kk] = fragA(P, mf + 1, kk); }
    };
    auto loadB = [&](int P) {
#pragma unroll
        for (int nf = 0; nf < 4; ++nf)
#pragma unroll
            for (int kk = 0; kk < 2; ++kk) bF[nf][kk] = fragB(P, nf, kk);
    };

    // ---------------- prologue: A(0),B(0) -> buf0 ; B(1) -> buf1 ----------------
    stage_A(0, 0);
    stage_B(0, 0, 0); stage_B(0, 1, 0);
    stage_B(1, 0, 1); stage_B(1, 1, 1);
    SFENCE(); VM4(); SFENCE();            // A(0),B(0) landed; B(1) may fly
    SBAR();

    // ---------------- main loop: 24 K-tiles, fully unrolled ----------------
#pragma unroll
    for (int j = 0; j < 24; ++j) {
        const int P = j & 1, PN = P ^ 1;
        // chunk 1: B frags + A mf0,1 ; stage A(j+1) -> PN ; MFMA mf0,1
        loadB(P);
        loadA(P, 0);
        if (j < 23) stage_A(PN, j + 1);
        cluster(0);
        // chunk 2: A mf2,3 ; stage B(j+2) -> P (B region dead after loadB) ; MFMA mf2,3
        loadA(P, 2);
        if (j < 22) { stage_B(P, 0, j + 2); stage_B(P, 1, j + 2); }
        cluster(2);
        // chunk 3: A mf4,5 ; MFMA mf4,5
        loadA(P, 4);
        cluster(4);
        // chunk 4: A mf6,7 ; MFMA mf6,7 ; counted wait ; barrier
        loadA(P, 6);
        cluster(6);
        SFENCE();
        if (j < 22) { VM4(); } else { VM0(); }
        SFENCE();
        SBAR();
    }

    // ---------------- epilogue: lane-local gates; LDS exchange for dir combine ----
    const float w0 = wsum[0], w1 = wsum[1];
    const int   d  = wn >> 1;
    const float* cp = d ? cp1 : cp0;
    const float wd  = d ? w1 : w0;

    float rc[8][4], rh[8][4];
#pragma unroll
    for (int mf = 0; mf < 8; ++mf) {
        const int orow = by * 64 + wm * 32 + mf * 4 + g4;
        const float bi = b_i[orow], bff = b_f[orow], bg = b_g[orow], bo = b_o[orow];
#pragma unroll
        for (int nf = 0; nf < 4; ++nf) {
            const int scol = bcol + (wn & 1) * 64 + nf * 16 + l16;
            float i_ = sigmoid_f(acc[mf][nf][0] + bi);
            float f_ = sigmoid_f(acc[mf][nf][1] + bff);
            float g_ = tanh_f  (acc[mf][nf][2] + bg);
            float o_ = sigmoid_f(acc[mf][nf][3] + bo);
            float cc = f_ * cp[(size_t)orow * NSAMP + scol] + i_ * g_;
            float hh = o_ * tanh_f(cc);
            rc[mf][nf] = wd * cc;
            rh[mf][nf] = wd * hh;
        }
    }

    float* ex = (float*)smem;
    const int rbase = (wm * 2 + (wn & 1)) * 4096;   // 16KB region per (wm, sample-half)
    if (d == 1) {
#pragma unroll
        for (int mf = 0; mf < 8; ++mf)
#pragma unroll
            for (int nf = 0; nf < 4; ++nf) {
                const int slot = rbase + (mf * 4 + nf) * 64 + lane;
                ex[slot]        = rc[mf][nf];
                ex[slot + 2048] = rh[mf][nf];
            }
    }
    SBAR();
    if (d == 0) {
#pragma unroll
        for (int mf = 0; mf < 8; ++mf) {
            const int orow = by * 64 + wm * 32 + mf * 4 + g4;
#pragma unroll
            for (int nf = 0; nf < 4; ++nf) {
                const int scol = bcol + (wn & 1) * 64 + nf * 16 + l16;
                const int slot = rbase + (mf * 4 + nf) * 64 + lane;
                out[(size_t)orow * NSAMP + scol] = rc[mf][nf] + ex[slot];
                out[(size_t)OUT_C * NSAMP + (size_t)orow * NSAMP + scol] = rh[mf][nf] + ex[slot + 2048];
            }
        }
    }
}

extern "C" void kernel_launch(void* const* d_in, const int* in_sizes, int n_in,
                              void* d_out, int out_size, void* d_ws, size_t ws_size,
                              hipStream_t stream) {
    (void)in_sizes; (void)n_in; (void)out_size; (void)ws_size;

    const float* x    = (const float*)d_in[0];
    const float* cp0  = (const float*)d_in[1];
    const float* hp0  = (const float*)d_in[2];
    const float* cp1  = (const float*)d_in[3];
    const float* hp1  = (const float*)d_in[4];
    const float* b_i  = (const float*)d_in[13];
    const float* b_f  = (const float*)d_in[14];
    const float* b_g  = (const float*)d_in[15];
    const float* b_o  = (const float*)d_in[16];
    const float* wsum = (const float*)d_in[17];
    float* out = (float*)d_out;

    // workspace: xT 8MB @0, h0T 16MB @8M, h1T 16MB @24M, Ap 12MB @40M
    char* ws = (char*)d_ws;
    unsigned short* xT  = (unsigned short*)(ws);
    unsigned short* h0T = (unsigned short*)(ws + (size_t)8  * 1024 * 1024);
    unsigned short* h1T = (unsigned short*)(ws + (size_t)24 * 1024 * 1024);
    unsigned short* Ap  = (unsigned short*)(ws + (size_t)40 * 1024 * 1024);

    dim3 tb(32, 8);
    tcvt3_kernel<<<dim3(NSAMP / 32, 80), tb, 0, stream>>>(x, hp0, hp1, xT, h0T, h1T);

    packA_kernel<<<(4096 * 192) / 256, 256, 0, stream>>>(
        (const float*)d_in[5], (const float*)d_in[6], (const float*)d_in[7], (const float*)d_in[8],
        (const float*)d_in[9], (const float*)d_in[10], (const float*)d_in[11], (const float*)d_in[12],
        Ap);

    mdlstm_main<<<dim3(NSAMP / 128, OUT_C / 64), 512, 0, stream>>>(
        Ap, xT, h0T, h1T, b_i, b_f, b_g, b_o, cp0, cp1, wsum, out);
}